// Round 5
// baseline (1086.303 us; speedup 1.0000x reference)
//
#include <hip/hip_runtime.h>

#define SHFL16(v, k) __shfl((v), (k), 16)
#define FENCE() asm volatile("" ::: "memory")
#define SB() __builtin_amdgcn_sched_barrier(0)

// per-item LDS layout (dwords). Row stride 16 (M1/M2/C), 8 (S4).
// Item stride 728 == 24 (mod 32): the wave's 4 groups hit disjoint bank
// quartets on uniform b128 broadcasts. 4 items/block -> 11648 B LDS ->
// 13 blocks/CU.
#define STR     728
#define OFF_M1    0   // P -> Pp -> Pn        (15 rows x 16)
#define OFF_M2  240   // A -> IKC             (15 rows x 16)
#define OFF_C   480   // C                    (6 rows x 16)
#define OFF_S4  576   // B -> PpCt -> K       (15 rows x 8; dword6 = xp stage)
#define OFF_VX  696   // x vector (16)
#define OFF_VU  712   // u vector (6 + pad)

__device__ __forceinline__ float dot15(const float* Lr, const float* v) {
    float4 x0 = *(const float4*)(Lr);
    float4 x1 = *(const float4*)(Lr + 4);
    float4 x2 = *(const float4*)(Lr + 8);
    float4 x3 = *(const float4*)(Lr + 12);
    return v[0]*x0.x + v[1]*x0.y + v[2]*x0.z + v[3]*x0.w
         + v[4]*x1.x + v[5]*x1.y + v[6]*x1.z + v[7]*x1.w
         + v[8]*x2.x + v[9]*x2.y + v[10]*x2.z + v[11]*x2.w
         + v[12]*x3.x + v[13]*x3.y + v[14]*x3.z;
}

__device__ __forceinline__ void rd15(const float* Lr, float* v) {
    float4 x0 = *(const float4*)(Lr);
    float4 x1 = *(const float4*)(Lr + 4);
    float4 x2 = *(const float4*)(Lr + 8);
    float4 x3 = *(const float4*)(Lr + 12);
    v[0]=x0.x; v[1]=x0.y; v[2]=x0.z; v[3]=x0.w;
    v[4]=x1.x; v[5]=x1.y; v[6]=x1.z; v[7]=x1.w;
    v[8]=x2.x; v[9]=x2.y; v[10]=x2.z; v[11]=x2.w;
    v[12]=x3.x; v[13]=x3.y; v[14]=x3.z;
}

__device__ __forceinline__ void axpy15(const float* Lr, float s, float* acc) {
    float4 x0 = *(const float4*)(Lr);
    float4 x1 = *(const float4*)(Lr + 4);
    float4 x2 = *(const float4*)(Lr + 8);
    float4 x3 = *(const float4*)(Lr + 12);
    acc[0]  += s*x0.x; acc[1]  += s*x0.y; acc[2]  += s*x0.z; acc[3]  += s*x0.w;
    acc[4]  += s*x1.x; acc[5]  += s*x1.y; acc[6]  += s*x1.z; acc[7]  += s*x1.w;
    acc[8]  += s*x2.x; acc[9]  += s*x2.y; acc[10] += s*x2.z; acc[11] += s*x2.w;
    acc[12] += s*x3.x; acc[13] += s*x3.y; acc[14] += s*x3.z;
}

__device__ __forceinline__ float dot6(const float* Lr, const float* v) {
    float4 x0 = *(const float4*)(Lr);
    float2 x1 = *(const float2*)(Lr + 4);
    return v[0]*x0.x + v[1]*x0.y + v[2]*x0.z + v[3]*x0.w + v[4]*x1.x + v[5]*x1.y;
}

__device__ __forceinline__ void wrow15(float* Lr, const float* v) {
    *(float4*)(Lr)      = make_float4(v[0], v[1], v[2], v[3]);
    *(float4*)(Lr + 4)  = make_float4(v[4], v[5], v[6], v[7]);
    *(float4*)(Lr + 8)  = make_float4(v[8], v[9], v[10], v[11]);
    *(float4*)(Lr + 12) = make_float4(v[12], v[13], v[14], 0.f);
}

__device__ __forceinline__ void wrow6(float* Lr, const float* v) {
    *(float4*)(Lr)     = make_float4(v[0], v[1], v[2], v[3]);
    *(float2*)(Lr + 4) = make_float2(v[4], v[5]);
}

__global__ void ekf_kernel(
    const float* __restrict__ g_state, const float* __restrict__ g_obs,
    const float* __restrict__ g_u,     const float* __restrict__ g_P,
    const float* __restrict__ g_A,     const float* __restrict__ g_B,
    const float* __restrict__ g_C,     const float* __restrict__ g_D,
    const float* __restrict__ g_c1,    const float* __restrict__ g_c2,
    const float* __restrict__ g_Q,     const float* __restrict__ g_R,
    float* __restrict__ o_xp, float* __restrict__ o_Pn, int bn)
{
    __shared__ __align__(16) float lds[4 * STR];
    const int tid = threadIdx.x;        // 64-thread block = ONE wave
    const int ib0 = blockIdx.x * 4;
    const int nIt = min(4, bn - ib0);

    const int g   = tid >> 4;
    const int r   = tid & 15;
    const int itc = ib0 + ((g < nIt) ? g : (nIt - 1));
    const int rc  = r < 15 ? r : 14;
    const int rc6 = r < 6 ? r : 5;
    float* L = lds + g * STR;

    // ---- per-lane small global loads ----
    float b[6], q[6], rr[6], dd[6];
    {
        const float* Bb = g_B + (size_t)itc * 90 + rc * 6;
        const float* Qb = g_Q + (size_t)itc * 36 + rc6 * 6;
        const float* Rb = g_R + (size_t)itc * 36 + rc6 * 6;
        const float* Db = g_D + (size_t)itc * 36 + rc6 * 6;
        #pragma unroll
        for (int j = 0; j < 6; ++j) { b[j]=Bb[j]; q[j]=Qb[j]; rr[j]=Rb[j]; dd[j]=Db[j]; }
    }
    float x    = g_state[(size_t)itc * 15 + rc];
    float uu   = g_u[(size_t)itc * 6 + rc6];
    float c1v  = g_c1[(size_t)itc * 15 + rc];
    float obsv = g_obs[(size_t)itc * 6 + rc6];
    float c2v  = g_c2[(size_t)itc * 6 + rc6];

    // ---- coalesced staging: P -> M1, A -> M2, C -> C ----
    {
        const float* gp = g_P + (size_t)ib0 * 225;
        const float* ga = g_A + (size_t)ib0 * 225;
        const int lim = nIt * 225;
        for (int i = tid; i < lim; i += 64) {
            int it = i / 225, idx = i - it * 225;
            int rw = idx / 15, j = idx - rw * 15;
            lds[it * STR + OFF_M1 + rw * 16 + j] = gp[i];
        }
        for (int i = tid; i < lim; i += 64) {
            int it = i / 225, idx = i - it * 225;
            int rw = idx / 15, j = idx - rw * 15;
            lds[it * STR + OFF_M2 + rw * 16 + j] = ga[i];
        }
        const float* gc = g_C + (size_t)ib0 * 90;
        const int limc = nIt * 90;
        for (int i = tid; i < limc; i += 64) {
            int it = i / 90, idx = i - it * 90;
            int rw = idx / 15, j = idx - rw * 15;
            lds[it * STR + OFF_C + rw * 16 + j] = gc[i];
        }
    }
    if (r < 15) { wrow6(L + OFF_S4 + r * 8, b); L[OFF_VX + r] = x; }
    if (r == 15) L[OFF_VX + 15] = 0.f;
    if (r < 6)  L[OFF_VU + r] = uu;
    FENCE();   // single wave: lockstep + compiler ordering; no __syncthreads
    SB();

    // ================= phase 1: xp0, ev =================
    float xp, ev;
    {
        float xv[15];
        rd15(L + OFF_VX, xv);
        float u0 = L[OFF_VU+0], u1 = L[OFF_VU+1], u2 = L[OFF_VU+2];
        float u3 = L[OFF_VU+3], u4 = L[OFF_VU+4], u5 = L[OFF_VU+5];
        xp = c1v + dot15(L + OFF_M2 + rc * 16, xv)
           + b[0]*u0 + b[1]*u1 + b[2]*u2 + b[3]*u3 + b[4]*u4 + b[5]*u5;
        ev = obsv - c2v - dot15(L + OFF_C + rc6 * 16, xv)
           - (dd[0]*u0 + dd[1]*u1 + dd[2]*u2 + dd[3]*u3 + dd[4]*u4 + dd[5]*u5);
    }
    SB();

    // ================= phase 2: Pp = A P A^T + B Q B^T =================
    float pp[15];
    {
        float a[15];
        rd15(L + OFF_M2 + rc * 16, a);
        float y[15];
        #pragma unroll
        for (int j = 0; j < 15; ++j) y[j] = 0.f;
        #define AXY3(k0) do { axpy15(L+OFF_M1+(k0)*16, a[(k0)], y); \
                              axpy15(L+OFF_M1+((k0)+1)*16, a[(k0)+1], y); \
                              axpy15(L+OFF_M1+((k0)+2)*16, a[(k0)+2], y); SB(); } while(0)
        AXY3(0); AXY3(3); AXY3(6); AXY3(9); AXY3(12);
        #define PPD3(j0) do { pp[(j0)]   = dot15(L+OFF_M2+(j0)*16, y); \
                              pp[(j0)+1] = dot15(L+OFF_M2+((j0)+1)*16, y); \
                              pp[(j0)+2] = dot15(L+OFF_M2+((j0)+2)*16, y); SB(); } while(0)
        PPD3(0); PPD3(3); PPD3(6); PPD3(9); PPD3(12);
    }
    {
        float z[6];
        #pragma unroll
        for (int j = 0; j < 6; ++j) z[j] = 0.f;
        #pragma unroll
        for (int k = 0; k < 6; ++k) {
            float bk = b[k];
            #pragma unroll
            for (int j = 0; j < 6; ++j) z[j] += bk * SHFL16(q[j], k);
        }
        #define PZ3(j0) do { pp[(j0)]   += dot6(L+OFF_S4+(j0)*8, z); \
                             pp[(j0)+1] += dot6(L+OFF_S4+((j0)+1)*8, z); \
                             pp[(j0)+2] += dot6(L+OFF_S4+((j0)+2)*8, z); SB(); } while(0)
        PZ3(0); PZ3(3); PZ3(6); PZ3(9); PZ3(12);
    }
    FENCE();
    if (r < 15) wrow15(L + OFF_M1 + r * 16, pp);   // Pp -> M1 (P dead)
    FENCE(); SB();

    // ================= phase 3: K =================
    float ppct[6];
    ppct[0] = dot15(L+OFF_C+0*16, pp); ppct[1] = dot15(L+OFF_C+1*16, pp);
    ppct[2] = dot15(L+OFF_C+2*16, pp); SB();
    ppct[3] = dot15(L+OFF_C+3*16, pp); ppct[4] = dot15(L+OFF_C+4*16, pp);
    ppct[5] = dot15(L+OFF_C+5*16, pp); SB();
    FENCE();
    if (r < 15) wrow6(L + OFF_S4 + r * 8, ppct);   // PpCt -> S4 (B dead)
    FENCE(); SB();

    float sm[12];
    #pragma unroll
    for (int j = 0; j < 6; ++j) { sm[j] = rr[j]; sm[6 + j] = (r == j) ? 1.f : 0.f; }
    {
        float c[15];
        rd15(L + OFF_C + rc6 * 16, c);
        #define SMK(k) do { const float* Pk = L + OFF_S4 + (k) * 8; \
            float4 v0 = *(const float4*)(Pk); float2 v1 = *(const float2*)(Pk + 4); \
            float ck = c[(k)]; \
            sm[0] += ck * v0.x; sm[1] += ck * v0.y; sm[2] += ck * v0.z; \
            sm[3] += ck * v0.w; sm[4] += ck * v1.x; sm[5] += ck * v1.y; } while(0)
        SMK(0); SMK(1); SMK(2); SB();
        SMK(3); SMK(4); SMK(5); SB();
        SMK(6); SMK(7); SMK(8); SB();
        SMK(9); SMK(10); SMK(11); SB();
        SMK(12); SMK(13); SMK(14); SB();
    }
    // Gauss-Jordan invert S (SPD -> no pivoting)
    #pragma unroll
    for (int k = 0; k < 6; ++k) {
        float piv = SHFL16(sm[k], k);
        float ip  = 1.f / piv;
        float f   = sm[k];
        #pragma unroll
        for (int j = 0; j < 12; ++j) {
            float prj = SHFL16(sm[j], k) * ip;
            sm[j] = (r == k) ? prj : (sm[j] - f * prj);
        }
    }
    float kk[6];
    #pragma unroll
    for (int j = 0; j < 6; ++j) kk[j] = 0.f;
    #pragma unroll
    for (int k = 0; k < 6; ++k) {
        float pk = ppct[k];
        #pragma unroll
        for (int j = 0; j < 6; ++j) kk[j] += pk * SHFL16(sm[6 + j], k);
    }
    FENCE();
    if (r < 15) wrow6(L + OFF_S4 + r * 8, kk);     // K -> S4 (PpCt dead)
    FENCE();
    #pragma unroll
    for (int j = 0; j < 6; ++j) xp += kk[j] * SHFL16(ev, j);
    SB();

    // ================= phase 4: Pn = IKC Pp IKC^T + K R K^T =================
    float pn[15];
    {
        float ikc[15];
        #pragma unroll
        for (int j = 0; j < 15; ++j) ikc[j] = (r == j) ? 1.f : 0.f;
        axpy15(L+OFF_C+0*16, -kk[0], ikc); axpy15(L+OFF_C+1*16, -kk[1], ikc);
        axpy15(L+OFF_C+2*16, -kk[2], ikc); SB();
        axpy15(L+OFF_C+3*16, -kk[3], ikc); axpy15(L+OFF_C+4*16, -kk[4], ikc);
        axpy15(L+OFF_C+5*16, -kk[5], ikc); SB();
        FENCE();
        if (r < 15) wrow15(L + OFF_M2 + r * 16, ikc);  // IKC -> M2 (A dead)
        FENCE(); SB();

        float t3[15];
        #pragma unroll
        for (int j = 0; j < 15; ++j) t3[j] = 0.f;
        #define T33(k0) do { axpy15(L+OFF_M1+(k0)*16, ikc[(k0)], t3); \
                             axpy15(L+OFF_M1+((k0)+1)*16, ikc[(k0)+1], t3); \
                             axpy15(L+OFF_M1+((k0)+2)*16, ikc[(k0)+2], t3); SB(); } while(0)
        T33(0); T33(3); T33(6); T33(9); T33(12);
        #define PN3(j0) do { pn[(j0)]   = dot15(L+OFF_M2+(j0)*16, t3); \
                             pn[(j0)+1] = dot15(L+OFF_M2+((j0)+1)*16, t3); \
                             pn[(j0)+2] = dot15(L+OFF_M2+((j0)+2)*16, t3); SB(); } while(0)
        PN3(0); PN3(3); PN3(6); PN3(9); PN3(12);
    }
    {
        float kr[6];
        #pragma unroll
        for (int j = 0; j < 6; ++j) kr[j] = 0.f;
        #pragma unroll
        for (int k = 0; k < 6; ++k) {
            float kkk = kk[k];
            #pragma unroll
            for (int j = 0; j < 6; ++j) kr[j] += kkk * SHFL16(rr[j], k);
        }
        #define PK3(j0) do { pn[(j0)]   += dot6(L+OFF_S4+(j0)*8, kr); \
                             pn[(j0)+1] += dot6(L+OFF_S4+((j0)+1)*8, kr); \
                             pn[(j0)+2] += dot6(L+OFF_S4+((j0)+2)*8, kr); SB(); } while(0)
        PK3(0); PK3(3); PK3(6); PK3(9); PK3(12);
    }

    // ---- stage results: Pn -> M1, xp -> S4 dword 6 ----
    FENCE();
    if (r < 15) {
        wrow15(L + OFF_M1 + r * 16, pn);
        L[OFF_S4 + r * 8 + 6] = xp;
    }
    FENCE(); SB();

    // ---- coalesced stores ----
    {
        float* gpn = o_Pn + (size_t)ib0 * 225;
        const int lim = nIt * 225;
        for (int i = tid; i < lim; i += 64) {
            int it = i / 225, idx = i - it * 225;
            int rw = idx / 15, j = idx - rw * 15;
            gpn[i] = lds[it * STR + OFF_M1 + rw * 16 + j];
        }
        float* gxp = o_xp + (size_t)ib0 * 15;
        const int lim2 = nIt * 15;
        for (int i = tid; i < lim2; i += 64) {
            int it = i / 15, rw = i - it * 15;
            gxp[i] = lds[it * STR + OFF_S4 + rw * 8 + 6];
        }
    }
}

extern "C" void kernel_launch(void* const* d_in, const int* in_sizes, int n_in,
                              void* d_out, int out_size, void* d_ws, size_t ws_size,
                              hipStream_t stream) {
    const float* g_state = (const float*)d_in[0];
    const float* g_obs   = (const float*)d_in[1];
    const float* g_u     = (const float*)d_in[2];
    const float* g_P     = (const float*)d_in[3];
    const float* g_A     = (const float*)d_in[4];
    const float* g_B     = (const float*)d_in[5];
    const float* g_C     = (const float*)d_in[6];
    const float* g_D     = (const float*)d_in[7];
    const float* g_c1    = (const float*)d_in[8];
    const float* g_c2    = (const float*)d_in[9];
    const float* g_Q     = (const float*)d_in[10];
    const float* g_R     = (const float*)d_in[11];

    const int bn = in_sizes[0] / 15;
    float* o_xp = (float*)d_out;
    float* o_pn = o_xp + (size_t)bn * 15;

    const int blocks = (bn + 3) / 4;   // 4 items per 64-thread (1-wave) block
    ekf_kernel<<<blocks, 64, 0, stream>>>(
        g_state, g_obs, g_u, g_P, g_A, g_B, g_C, g_D, g_c1, g_c2, g_Q, g_R,
        o_xp, o_pn, bn);
}

// Round 6
// 859.223 us; speedup vs baseline: 1.2643x; 1.2643x over previous
//
#include <hip/hip_runtime.h>

#define SHFL16(v, k) __shfl((v), (k), 16)
#define FENCE() asm volatile("" ::: "memory")
#define SB() __builtin_amdgcn_sched_barrier(0)

// per-item LDS layout (dwords). Row stride 20 for 15-col matrices: row-write
// banks spread over 8 quartets {0,20,8,28,16,4,24,12} -> balanced b128 writes.
// Item stride 840 == 8 (mod 32): the wave's 4 groups hit disjoint bank
// quartets on uniform broadcasts. 4 items/block -> 13440 B LDS -> 12 blocks/CU
// = 3 waves/SIMD, matching amdgpu_waves_per_eu(2,3).
#define STR     840
#define OFF_M1    0   // P -> Pp -> Pn        (15 rows x 20)
#define OFF_M2  300   // A -> IKC             (15 rows x 20)
#define OFF_C   600   // C                    (6 rows x 16)
#define OFF_S4  696   // B -> PpCt -> K       (15 rows x 8; dword6 = xp stage)
#define OFF_VX  816   // x vector (16)
#define OFF_VU  832   // u vector (6 + pad)

__device__ __forceinline__ float dot15(const float* Lr, const float* v) {
    float4 x0 = *(const float4*)(Lr);
    float4 x1 = *(const float4*)(Lr + 4);
    float4 x2 = *(const float4*)(Lr + 8);
    float4 x3 = *(const float4*)(Lr + 12);
    return v[0]*x0.x + v[1]*x0.y + v[2]*x0.z + v[3]*x0.w
         + v[4]*x1.x + v[5]*x1.y + v[6]*x1.z + v[7]*x1.w
         + v[8]*x2.x + v[9]*x2.y + v[10]*x2.z + v[11]*x2.w
         + v[12]*x3.x + v[13]*x3.y + v[14]*x3.z;
}

__device__ __forceinline__ void rd15(const float* Lr, float* v) {
    float4 x0 = *(const float4*)(Lr);
    float4 x1 = *(const float4*)(Lr + 4);
    float4 x2 = *(const float4*)(Lr + 8);
    float4 x3 = *(const float4*)(Lr + 12);
    v[0]=x0.x; v[1]=x0.y; v[2]=x0.z; v[3]=x0.w;
    v[4]=x1.x; v[5]=x1.y; v[6]=x1.z; v[7]=x1.w;
    v[8]=x2.x; v[9]=x2.y; v[10]=x2.z; v[11]=x2.w;
    v[12]=x3.x; v[13]=x3.y; v[14]=x3.z;
}

__device__ __forceinline__ void axpy15(const float* Lr, float s, float* acc) {
    float4 x0 = *(const float4*)(Lr);
    float4 x1 = *(const float4*)(Lr + 4);
    float4 x2 = *(const float4*)(Lr + 8);
    float4 x3 = *(const float4*)(Lr + 12);
    acc[0]  += s*x0.x; acc[1]  += s*x0.y; acc[2]  += s*x0.z; acc[3]  += s*x0.w;
    acc[4]  += s*x1.x; acc[5]  += s*x1.y; acc[6]  += s*x1.z; acc[7]  += s*x1.w;
    acc[8]  += s*x2.x; acc[9]  += s*x2.y; acc[10] += s*x2.z; acc[11] += s*x2.w;
    acc[12] += s*x3.x; acc[13] += s*x3.y; acc[14] += s*x3.z;
}

__device__ __forceinline__ float dot6(const float* Lr, const float* v) {
    float4 x0 = *(const float4*)(Lr);
    float2 x1 = *(const float2*)(Lr + 4);
    return v[0]*x0.x + v[1]*x0.y + v[2]*x0.z + v[3]*x0.w + v[4]*x1.x + v[5]*x1.y;
}

__device__ __forceinline__ void wrow15(float* Lr, const float* v) {
    *(float4*)(Lr)      = make_float4(v[0], v[1], v[2], v[3]);
    *(float4*)(Lr + 4)  = make_float4(v[4], v[5], v[6], v[7]);
    *(float4*)(Lr + 8)  = make_float4(v[8], v[9], v[10], v[11]);
    *(float4*)(Lr + 12) = make_float4(v[12], v[13], v[14], 0.f);
}

__device__ __forceinline__ void wrow6(float* Lr, const float* v) {
    *(float4*)(Lr)     = make_float4(v[0], v[1], v[2], v[3]);
    *(float2*)(Lr + 4) = make_float2(v[4], v[5]);
}

__global__
__attribute__((amdgpu_flat_work_group_size(64, 64)))
__attribute__((amdgpu_waves_per_eu(2, 3)))
void ekf_kernel(
    const float* __restrict__ g_state, const float* __restrict__ g_obs,
    const float* __restrict__ g_u,     const float* __restrict__ g_P,
    const float* __restrict__ g_A,     const float* __restrict__ g_B,
    const float* __restrict__ g_C,     const float* __restrict__ g_D,
    const float* __restrict__ g_c1,    const float* __restrict__ g_c2,
    const float* __restrict__ g_Q,     const float* __restrict__ g_R,
    float* __restrict__ o_xp, float* __restrict__ o_Pn, int bn)
{
    __shared__ __align__(16) float lds[4 * STR];
    const int tid = threadIdx.x;        // 64-thread block = ONE wave
    const int ib0 = blockIdx.x * 4;
    const int nIt = min(4, bn - ib0);

    const int g   = tid >> 4;
    const int r   = tid & 15;
    const int itc = ib0 + ((g < nIt) ? g : (nIt - 1));
    const int rc  = r < 15 ? r : 14;
    const int rc6 = r < 6 ? r : 5;
    float* L = lds + g * STR;

    // ---- per-lane small global loads ----
    float b[6], q[6], rr[6], dd[6];
    {
        const float* Bb = g_B + (size_t)itc * 90 + rc * 6;
        const float* Qb = g_Q + (size_t)itc * 36 + rc6 * 6;
        const float* Rb = g_R + (size_t)itc * 36 + rc6 * 6;
        const float* Db = g_D + (size_t)itc * 36 + rc6 * 6;
        #pragma unroll
        for (int j = 0; j < 6; ++j) { b[j]=Bb[j]; q[j]=Qb[j]; rr[j]=Rb[j]; dd[j]=Db[j]; }
    }
    float x    = g_state[(size_t)itc * 15 + rc];
    float uu   = g_u[(size_t)itc * 6 + rc6];
    float c1v  = g_c1[(size_t)itc * 15 + rc];
    float obsv = g_obs[(size_t)itc * 6 + rc6];
    float c2v  = g_c2[(size_t)itc * 6 + rc6];

    // ---- coalesced staging: P -> M1, A -> M2, C -> C ----
    {
        const float* gp = g_P + (size_t)ib0 * 225;
        const float* ga = g_A + (size_t)ib0 * 225;
        const int lim = nIt * 225;
        for (int i = tid; i < lim; i += 64) {
            int it = i / 225, idx = i - it * 225;
            int rw = idx / 15, j = idx - rw * 15;
            lds[it * STR + OFF_M1 + rw * 20 + j] = gp[i];
        }
        for (int i = tid; i < lim; i += 64) {
            int it = i / 225, idx = i - it * 225;
            int rw = idx / 15, j = idx - rw * 15;
            lds[it * STR + OFF_M2 + rw * 20 + j] = ga[i];
        }
        const float* gc = g_C + (size_t)ib0 * 90;
        const int limc = nIt * 90;
        for (int i = tid; i < limc; i += 64) {
            int it = i / 90, idx = i - it * 90;
            int rw = idx / 15, j = idx - rw * 15;
            lds[it * STR + OFF_C + rw * 16 + j] = gc[i];
        }
    }
    if (r < 15) { wrow6(L + OFF_S4 + r * 8, b); L[OFF_VX + r] = x; }
    if (r == 15) L[OFF_VX + 15] = 0.f;
    if (r < 6)  L[OFF_VU + r] = uu;
    FENCE();   // single wave: lockstep + compiler ordering; no __syncthreads
    SB();

    // ================= phase 1: xp0, ev =================
    float xp, ev;
    {
        float xv[15];
        rd15(L + OFF_VX, xv);
        float u0 = L[OFF_VU+0], u1 = L[OFF_VU+1], u2 = L[OFF_VU+2];
        float u3 = L[OFF_VU+3], u4 = L[OFF_VU+4], u5 = L[OFF_VU+5];
        xp = c1v + dot15(L + OFF_M2 + rc * 20, xv)
           + b[0]*u0 + b[1]*u1 + b[2]*u2 + b[3]*u3 + b[4]*u4 + b[5]*u5;
        ev = obsv - c2v - dot15(L + OFF_C + rc6 * 16, xv)
           - (dd[0]*u0 + dd[1]*u1 + dd[2]*u2 + dd[3]*u3 + dd[4]*u4 + dd[5]*u5);
    }
    SB();

    // ================= phase 2: Pp = A P A^T + B Q B^T =================
    float pp[15];
    {
        float a[15];
        rd15(L + OFF_M2 + rc * 20, a);
        float y[15];
        #pragma unroll
        for (int j = 0; j < 15; ++j) y[j] = 0.f;
        #define AXY3(k0) do { axpy15(L+OFF_M1+(k0)*20, a[(k0)], y); \
                              axpy15(L+OFF_M1+((k0)+1)*20, a[(k0)+1], y); \
                              axpy15(L+OFF_M1+((k0)+2)*20, a[(k0)+2], y); SB(); } while(0)
        AXY3(0); AXY3(3); AXY3(6); AXY3(9); AXY3(12);
        #define PPD3(j0) do { pp[(j0)]   = dot15(L+OFF_M2+(j0)*20, y); \
                              pp[(j0)+1] = dot15(L+OFF_M2+((j0)+1)*20, y); \
                              pp[(j0)+2] = dot15(L+OFF_M2+((j0)+2)*20, y); SB(); } while(0)
        PPD3(0); PPD3(3); PPD3(6); PPD3(9); PPD3(12);
    }
    {
        float z[6];
        #pragma unroll
        for (int j = 0; j < 6; ++j) z[j] = 0.f;
        #pragma unroll
        for (int k = 0; k < 6; ++k) {
            float bk = b[k];
            #pragma unroll
            for (int j = 0; j < 6; ++j) z[j] += bk * SHFL16(q[j], k);
        }
        #define PZ3(j0) do { pp[(j0)]   += dot6(L+OFF_S4+(j0)*8, z); \
                             pp[(j0)+1] += dot6(L+OFF_S4+((j0)+1)*8, z); \
                             pp[(j0)+2] += dot6(L+OFF_S4+((j0)+2)*8, z); SB(); } while(0)
        PZ3(0); PZ3(3); PZ3(6); PZ3(9); PZ3(12);
    }
    FENCE();
    if (r < 15) wrow15(L + OFF_M1 + r * 20, pp);   // Pp -> M1 (P dead)
    FENCE(); SB();

    // ================= phase 3: K =================
    float ppct[6];
    ppct[0] = dot15(L+OFF_C+0*16, pp); ppct[1] = dot15(L+OFF_C+1*16, pp);
    ppct[2] = dot15(L+OFF_C+2*16, pp); SB();
    ppct[3] = dot15(L+OFF_C+3*16, pp); ppct[4] = dot15(L+OFF_C+4*16, pp);
    ppct[5] = dot15(L+OFF_C+5*16, pp); SB();
    FENCE();
    if (r < 15) wrow6(L + OFF_S4 + r * 8, ppct);   // PpCt -> S4 (B dead)
    FENCE(); SB();

    float sm[12];
    #pragma unroll
    for (int j = 0; j < 6; ++j) { sm[j] = rr[j]; sm[6 + j] = (r == j) ? 1.f : 0.f; }
    {
        float c[15];
        rd15(L + OFF_C + rc6 * 16, c);
        #define SMK(k) do { const float* Pk = L + OFF_S4 + (k) * 8; \
            float4 v0 = *(const float4*)(Pk); float2 v1 = *(const float2*)(Pk + 4); \
            float ck = c[(k)]; \
            sm[0] += ck * v0.x; sm[1] += ck * v0.y; sm[2] += ck * v0.z; \
            sm[3] += ck * v0.w; sm[4] += ck * v1.x; sm[5] += ck * v1.y; } while(0)
        SMK(0); SMK(1); SMK(2); SB();
        SMK(3); SMK(4); SMK(5); SB();
        SMK(6); SMK(7); SMK(8); SB();
        SMK(9); SMK(10); SMK(11); SB();
        SMK(12); SMK(13); SMK(14); SB();
    }
    // Gauss-Jordan invert S (SPD -> no pivoting)
    #pragma unroll
    for (int k = 0; k < 6; ++k) {
        float piv = SHFL16(sm[k], k);
        float ip  = 1.f / piv;
        float f   = sm[k];
        #pragma unroll
        for (int j = 0; j < 12; ++j) {
            float prj = SHFL16(sm[j], k) * ip;
            sm[j] = (r == k) ? prj : (sm[j] - f * prj);
        }
    }
    float kk[6];
    #pragma unroll
    for (int j = 0; j < 6; ++j) kk[j] = 0.f;
    #pragma unroll
    for (int k = 0; k < 6; ++k) {
        float pk = ppct[k];
        #pragma unroll
        for (int j = 0; j < 6; ++j) kk[j] += pk * SHFL16(sm[6 + j], k);
    }
    FENCE();
    if (r < 15) wrow6(L + OFF_S4 + r * 8, kk);     // K -> S4 (PpCt dead)
    FENCE();
    #pragma unroll
    for (int j = 0; j < 6; ++j) xp += kk[j] * SHFL16(ev, j);
    SB();

    // ================= phase 4: Pn = IKC Pp IKC^T + K R K^T =================
    float pn[15];
    {
        float ikc[15];
        #pragma unroll
        for (int j = 0; j < 15; ++j) ikc[j] = (r == j) ? 1.f : 0.f;
        axpy15(L+OFF_C+0*16, -kk[0], ikc); axpy15(L+OFF_C+1*16, -kk[1], ikc);
        axpy15(L+OFF_C+2*16, -kk[2], ikc); SB();
        axpy15(L+OFF_C+3*16, -kk[3], ikc); axpy15(L+OFF_C+4*16, -kk[4], ikc);
        axpy15(L+OFF_C+5*16, -kk[5], ikc); SB();
        FENCE();
        if (r < 15) wrow15(L + OFF_M2 + r * 20, ikc);  // IKC -> M2 (A dead)
        FENCE(); SB();

        float t3[15];
        #pragma unroll
        for (int j = 0; j < 15; ++j) t3[j] = 0.f;
        #define T33(k0) do { axpy15(L+OFF_M1+(k0)*20, ikc[(k0)], t3); \
                             axpy15(L+OFF_M1+((k0)+1)*20, ikc[(k0)+1], t3); \
                             axpy15(L+OFF_M1+((k0)+2)*20, ikc[(k0)+2], t3); SB(); } while(0)
        T33(0); T33(3); T33(6); T33(9); T33(12);
        #define PN3(j0) do { pn[(j0)]   = dot15(L+OFF_M2+(j0)*20, t3); \
                             pn[(j0)+1] = dot15(L+OFF_M2+((j0)+1)*20, t3); \
                             pn[(j0)+2] = dot15(L+OFF_M2+((j0)+2)*20, t3); SB(); } while(0)
        PN3(0); PN3(3); PN3(6); PN3(9); PN3(12);
    }
    {
        float kr[6];
        #pragma unroll
        for (int j = 0; j < 6; ++j) kr[j] = 0.f;
        #pragma unroll
        for (int k = 0; k < 6; ++k) {
            float kkk = kk[k];
            #pragma unroll
            for (int j = 0; j < 6; ++j) kr[j] += kkk * SHFL16(rr[j], k);
        }
        #define PK3(j0) do { pn[(j0)]   += dot6(L+OFF_S4+(j0)*8, kr); \
                             pn[(j0)+1] += dot6(L+OFF_S4+((j0)+1)*8, kr); \
                             pn[(j0)+2] += dot6(L+OFF_S4+((j0)+2)*8, kr); SB(); } while(0)
        PK3(0); PK3(3); PK3(6); PK3(9); PK3(12);
    }

    // ---- stage results: Pn -> M1, xp -> S4 dword 6 ----
    FENCE();
    if (r < 15) {
        wrow15(L + OFF_M1 + r * 20, pn);
        L[OFF_S4 + r * 8 + 6] = xp;
    }
    FENCE(); SB();

    // ---- coalesced stores ----
    {
        float* gpn = o_Pn + (size_t)ib0 * 225;
        const int lim = nIt * 225;
        for (int i = tid; i < lim; i += 64) {
            int it = i / 225, idx = i - it * 225;
            int rw = idx / 15, j = idx - rw * 15;
            gpn[i] = lds[it * STR + OFF_M1 + rw * 20 + j];
        }
        float* gxp = o_xp + (size_t)ib0 * 15;
        const int lim2 = nIt * 15;
        for (int i = tid; i < lim2; i += 64) {
            int it = i / 15, rw = i - it * 15;
            gxp[i] = lds[it * STR + OFF_S4 + rw * 8 + 6];
        }
    }
}

extern "C" void kernel_launch(void* const* d_in, const int* in_sizes, int n_in,
                              void* d_out, int out_size, void* d_ws, size_t ws_size,
                              hipStream_t stream) {
    const float* g_state = (const float*)d_in[0];
    const float* g_obs   = (const float*)d_in[1];
    const float* g_u     = (const float*)d_in[2];
    const float* g_P     = (const float*)d_in[3];
    const float* g_A     = (const float*)d_in[4];
    const float* g_B     = (const float*)d_in[5];
    const float* g_C     = (const float*)d_in[6];
    const float* g_D     = (const float*)d_in[7];
    const float* g_c1    = (const float*)d_in[8];
    const float* g_c2    = (const float*)d_in[9];
    const float* g_Q     = (const float*)d_in[10];
    const float* g_R     = (const float*)d_in[11];

    const int bn = in_sizes[0] / 15;
    float* o_xp = (float*)d_out;
    float* o_pn = o_xp + (size_t)bn * 15;

    const int blocks = (bn + 3) / 4;   // 4 items per 64-thread (1-wave) block
    ekf_kernel<<<blocks, 64, 0, stream>>>(
        g_state, g_obs, g_u, g_P, g_A, g_B, g_C, g_D, g_c1, g_c2, g_Q, g_R,
        o_xp, o_pn, bn);
}